// Round 7
// baseline (181.106 us; speedup 1.0000x reference)
//
#include <hip/hip_runtime.h>
#include <hip/hip_bf16.h>

#define TGT 256
#define BSZ 8
#define E   256
#define SRC 4096

typedef __attribute__((ext_vector_type(8))) short           bf16x8;
typedef __attribute__((ext_vector_type(4))) float           f32x4;
typedef __attribute__((ext_vector_type(4))) float           f4;
typedef __attribute__((ext_vector_type(4))) unsigned short  u16x4;

__device__ inline unsigned short f2b(float x) {
    union { __hip_bfloat16 h; unsigned short u; } cv;
    cv.h = __float2bfloat16(x);
    return cv.u;
}

__device__ inline bf16x8 cvt8v(const float* __restrict__ p) {
    f4 lo = *(const f4*)p;
    f4 hi = *(const f4*)(p + 4);
    bf16x8 r;
    #pragma unroll
    for (int j = 0; j < 4; ++j) { r[j] = (short)f2b(lo[j]); r[4 + j] = (short)f2b(hi[j]); }
    return r;
}

// ---------------------------------------------------------------------------
// prep: grid 192 x 128 thr.
//  bx<64 : W(E,E) fp32 -> wf in B-fragment order (bf16)  [layout verified R3-R6]
//  bx>=64: out0[t,b,e] = bias[e]  (mega atomically accumulates on top)
// ---------------------------------------------------------------------------
__global__ __launch_bounds__(128) void prep(
    const float* __restrict__ wgt, const float* __restrict__ bias,
    unsigned short* __restrict__ wf, float* __restrict__ out0)
{
    const int tid = threadIdx.x;
    if (blockIdx.x < 64) {
        int o    = blockIdx.x * 128 + tid;   // 0..8191
        int et   = o >> 9;
        int ks   = (o >> 6) & 7;
        int lane = o & 63;
        int quad = lane >> 4, l15 = lane & 15;
        *(bf16x8*)&wf[(size_t)o * 8] =
            cvt8v(wgt + (size_t)(et * 16 + l15) * E + ks * 32 + quad * 8);
    } else {
        int bx = blockIdx.x - 64;            // 0..127
        #pragma unroll
        for (int s = 0; s < 8; ++s) {
            int f4i = s * 16384 + bx * 128 + tid;       // 0..131071
            *(f4*)(out0 + (size_t)f4i * 4) = *(const f4*)(bias + (f4i & 63) * 4);
        }
    }
}

// ---------------------------------------------------------------------------
// mega: ONE kernel per (b, kc) with kc = 32 chunks of 128 k. Grid 256 = 1/CU.
// Phase A (2 barriers total):
//   A1: stage V[k0..k0+128) x 256e -> vt (bf16 LDS)
//   A2: wave w loads A-frags for its 16 k-rows
//   A3: VW = Vchunk @ W^T (B-frags from wf, prefetch-pipelined), D written
//       into vwB LDS directly in B-FRAG LAYOUT (R6-verified index algebra:
//       k = w*16+quad*4+r  ->  q=w>>1, lane'=((w&1)*2+(quad>>1))*16+l15,
//       j=(quad&1)*4+r  => u16x4 store)
// Phase B (NO block barriers; waves free-run):
//   wave w handles t-tiles tt = w, w+8: per-wave M[16x128] staging into its
//   private mt region (reuses vt space), out1 copy, 16 et x 4 q MFMAs with
//   B-frags from vwB (LDS), 4 atomicAdd per et into bias-seeded out0.
// Removes: vwf HBM round-trip (33.6 MB), 134-268 MB L2 B-frag re-reads,
// 295->16 MB wf re-reads, one launch, all phase-B barriers.
// LDS: vt 67.6 KB + vwB 65.5 KB = 133 KB -> 1 block/CU.
// ---------------------------------------------------------------------------
#define VTP 264   // vt pitch u16 (528 B rows, 16B-aligned)
#define MTP 136   // mt pitch u16 (272 B rows, 16B-aligned)

__global__ __launch_bounds__(512, 2) void mega(
    const float* __restrict__ value,
    const float* __restrict__ mask,
    const unsigned short* __restrict__ wf,
    float* __restrict__ out1,
    float* __restrict__ out0)
{
    __shared__ unsigned short vt[128 * VTP];        // 67.6 KB (phase B: 8x mt)
    __shared__ unsigned short vwB[16 * 4 * 64 * 8]; // 65.5 KB, B-frag layout

    const int bx  = blockIdx.x;
    const int b   = bx & 7;                 // XCD swizzle: same-b -> same XCD
    const int kc  = bx >> 3;                // 0..31
    const int k0  = kc * 128;
    const int tid = threadIdx.x;
    const int w    = tid >> 6;              // wave 0..7
    const int lane = tid & 63;
    const int quad = lane >> 4;
    const int l15  = lane & 15;

    // ---- A1: stage V chunk (128 k-rows x 256 e) -> vt bf16 (coalesced)
    #pragma unroll
    for (int i = 0; i < 16; ++i) {
        int lin = i * 512 + tid;            // 0..8191
        int row = lin >> 6;                 // k-local 0..127
        int c4  = lin & 63;
        f4 v = *(const f4*)(value + (size_t)(k0 + row) * (BSZ * E)
                                  + (size_t)b * E + c4 * 4);
        u16x4 pk;
        #pragma unroll
        for (int j = 0; j < 4; ++j) pk[j] = f2b(v[j]);
        *(u16x4*)&vt[row * VTP + c4 * 4] = pk;
    }
    __syncthreads();

    // ---- A2: A-frags for wave's 16 k-rows (m = k-row, contraction = e)
    bf16x8 a[8];
    #pragma unroll
    for (int ks = 0; ks < 8; ++ks)
        a[ks] = *(const bf16x8*)&vt[(w * 16 + l15) * VTP + ks * 32 + quad * 8];

    // ---- A3: VW = Vchunk @ W^T, written straight into vwB (B-frag layout)
    {
        const unsigned short* bfw = wf + (size_t)lane * 8;
        const int qh = w >> 1;
        const int lp = ((w & 1) * 2 + (quad >> 1)) * 16 + l15;
        const int j0 = (quad & 1) * 4;
        bf16x8 bb[8], nb[8];
        #pragma unroll
        for (int ks = 0; ks < 8; ++ks)
            bb[ks] = *(const bf16x8*)(bfw + (size_t)ks * 512);
        #pragma unroll
        for (int et = 0; et < 16; ++et) {
            if (et < 15) {
                #pragma unroll
                for (int ks = 0; ks < 8; ++ks)
                    nb[ks] = *(const bf16x8*)(bfw + (size_t)((et + 1) * 8 + ks) * 512);
            }
            f32x4 acc = {};
            #pragma unroll
            for (int ks = 0; ks < 8; ++ks)
                acc = __builtin_amdgcn_mfma_f32_16x16x32_bf16(a[ks], bb[ks], acc, 0, 0, 0);
            u16x4 pk;
            #pragma unroll
            for (int r = 0; r < 4; ++r) pk[r] = f2b(acc[r]);
            *(u16x4*)&vwB[(((size_t)et * 4 + qh) * 64 + lp) * 8 + j0] = pk;
            if (et < 15) {
                #pragma unroll
                for (int ks = 0; ks < 8; ++ks) bb[ks] = nb[ks];
            }
        }
    }
    __syncthreads();

    // ---- phase B: per-wave t-tiles, no block barriers
    unsigned short* mt = &vt[w * (16 * MTP)];       // wave-private 16x128 region
    #pragma unroll
    for (int it = 0; it < 2; ++it) {
        const int tt = w + it * 8;                  // 0..15
        const int t0 = tt * 16;
        const float* mb = mask + (size_t)b * TGT * SRC + (size_t)t0 * SRC + k0;
        float*       ob = out1 + (size_t)b * TGT * SRC + (size_t)t0 * SRC + k0;

        // stage M[16 x 128] -> regs -> mt (bf16) + out1 copy (coalesced)
        f4 mv[8];
        #pragma unroll
        for (int i = 0; i < 8; ++i) {
            int idx = i * 64 + lane;                // 0..511
            int row = idx >> 5, c4 = idx & 31;
            mv[i] = *(const f4*)(mb + (size_t)row * SRC + c4 * 4);
        }
        #pragma unroll
        for (int i = 0; i < 8; ++i) {
            int idx = i * 64 + lane;
            int row = idx >> 5, c4 = idx & 31;
            u16x4 pk;
            #pragma unroll
            for (int j = 0; j < 4; ++j) pk[j] = f2b(mv[i][j]);
            *(u16x4*)&mt[row * MTP + c4 * 4] = pk;
            *(f4*)(ob + (size_t)row * SRC + c4 * 4) = mv[i];
        }

        // A-frags for this t-tile (same-wave LDS write->read, lgkm-ordered)
        bf16x8 a4[4];
        #pragma unroll
        for (int q = 0; q < 4; ++q)
            a4[q] = *(const bf16x8*)&mt[l15 * MTP + q * 32 + quad * 8];

        // 16 et x 4 q MFMAs; atomic epilogue per et
        #pragma unroll
        for (int et = 0; et < 16; ++et) {
            f32x4 acc = {};
            #pragma unroll
            for (int q = 0; q < 4; ++q) {
                bf16x8 vb = *(const bf16x8*)&vwB[(((size_t)et * 4 + q) * 64 + lane) * 8];
                acc = __builtin_amdgcn_mfma_f32_16x16x32_bf16(a4[q], vb, acc, 0, 0, 0);
            }
            const int ecol = et * 16 + l15;
            #pragma unroll
            for (int r = 0; r < 4; ++r) {
                int t = t0 + quad * 4 + r;
                atomicAdd(out0 + (size_t)t * (BSZ * E) + (size_t)b * E + ecol, acc[r]);
            }
        }
    }
}

// ---------------------------------------------------------------------------
extern "C" void kernel_launch(void* const* d_in, const int* in_sizes, int n_in,
                              void* d_out, int out_size, void* d_ws, size_t ws_size,
                              hipStream_t stream)
{
    // inputs: 0=query(unused) 1=key(unused) 2=value 3=proposal_mask 4=W 5=bias
    const float* value = (const float*)d_in[2];
    const float* mask  = (const float*)d_in[3];
    const float* wgt   = (const float*)d_in[4];
    const float* bias  = (const float*)d_in[5];

    float* out0 = (float*)d_out;                              // (256,8,256)
    float* out1 = (float*)d_out + (size_t)TGT * BSZ * E;      // (8,256,4096)

    // ws layout: wf bf16 128 KB (only workspace use)
    unsigned short* wf = (unsigned short*)d_ws;

    prep<<<192, 128, 0, stream>>>(wgt, bias, wf, out0);
    mega<<<256, 512, 0, stream>>>(value, mask, wf, out1, out0);
}

// Round 8
// 148.259 us; speedup vs baseline: 1.2215x; 1.2215x over previous
//
#include <hip/hip_runtime.h>
#include <hip/hip_bf16.h>

#define TGT 256
#define BSZ 8
#define E   256
#define SRC 4096

typedef __attribute__((ext_vector_type(8))) short           bf16x8;
typedef __attribute__((ext_vector_type(4))) float           f32x4;
typedef __attribute__((ext_vector_type(4))) float           f4;
typedef __attribute__((ext_vector_type(8))) unsigned short  u16x8;
typedef __attribute__((ext_vector_type(4))) unsigned short  u16x4;

__device__ inline unsigned short f2b(float x) {
    union { __hip_bfloat16 h; unsigned short u; } cv;
    cv.h = __float2bfloat16(x);
    return cv.u;
}

__device__ inline bf16x8 cvt8v(const float* __restrict__ p) {
    f4 lo = *(const f4*)p;
    f4 hi = *(const f4*)(p + 4);
    bf16x8 r;
    #pragma unroll
    for (int j = 0; j < 4; ++j) { r[j] = (short)f2b(lo[j]); r[4 + j] = (short)f2b(hi[j]); }
    return r;
}

// ---------------------------------------------------------------------------
// prep: grid (64, 9).  [R0 verbatim — measured-good ~10 us, ~79% stream BW]
//  by<8 : v_frag — value(SRC,BSZ,E) fp32 -> vtf in B-fragment order (bf16)
//  by==8: w_frag — W(E,E) fp32 -> wf in B-fragment order (bf16)
// ---------------------------------------------------------------------------
__global__ __launch_bounds__(256) void prep(
    const float* __restrict__ value, const float* __restrict__ wgt,
    unsigned short* __restrict__ vtf, unsigned short* __restrict__ wf)
{
    const int tid = threadIdx.x;

    if (blockIdx.y == 8) {               // ---- W frag pass (64 tiny blocks)
        if (tid < 128) {
            int o    = blockIdx.x * 128 + tid;   // 0..8191
            int et   = o >> 9;
            int ks   = (o >> 6) & 7;
            int lane = o & 63;
            int quad = lane >> 4, l15 = lane & 15;
            bf16x8 v = cvt8v(wgt + (size_t)(et * 16 + l15) * E + ks * 32 + quad * 8);
            *(bf16x8*)&wf[(size_t)o * 8] = v;
        }
        return;
    }

    __shared__ unsigned short tile[64 * 264];   // pitch 264 u16
    const int kch = blockIdx.x;                 // 0..63
    const int b   = blockIdx.y;
    const int k0  = kch * 64;

    #pragma unroll
    for (int i = 0; i < 16; ++i) {
        int lin = i * 256 + tid;                // 0..4095
        int row = lin >> 6;                     // k-local 0..63
        int c4  = lin & 63;                     // e float4 idx
        f4 v = *(const f4*)(value + (size_t)(k0 + row) * (BSZ * E)
                                  + (size_t)b * E + c4 * 4);
        #pragma unroll
        for (int j = 0; j < 4; ++j) tile[row * 264 + c4 * 4 + j] = f2b(v[j]);
    }
    __syncthreads();

    #pragma unroll
    for (int i = 0; i < 8; ++i) {
        int o    = i * 256 + tid;               // 0..2047 octets
        int et   = o >> 7;
        int ksl  = (o >> 6) & 1;
        int lane = o & 63;
        int quad = lane >> 4, l15 = lane & 15;
        u16x8 pk;
        #pragma unroll
        for (int j = 0; j < 8; ++j)
            pk[j] = tile[(ksl * 32 + quad * 8 + j) * 264 + et * 16 + l15];
        size_t ks = (size_t)kch * 2 + ksl;
        *(u16x8*)&vtf[((((size_t)b * 16 + et) * 128 + ks) * 64 + lane) * 8] = pk;
    }
}

// ---------------------------------------------------------------------------
// gemm1: part[kc] = M_b[t-tile, kc-chunk] @ V_b[kc-chunk] + fused out1 copy.
// R0 structure (4-stage dbuf, 512 blocks x 512 thr, part-buffer epilogue)
// with ONE change: all 8 mask loads per thread are issued in a single
// prologue burst (128 B/thread in flight, 64 KB/block) instead of 2 loads
// per stage gated by each barrier. Theory: gemm1 ran at ~28% HBM because
// the per-CU read queue never filled (write-only fill hits 83%; read+store
// prep hits 79%). Stages then drain on staggered vmcnt under the MFMAs.
// ---------------------------------------------------------------------------
#define AP 136   // A pitch u16: 272 B rows (16B-aligned)

__global__ __launch_bounds__(512) void gemm1(
    const float* __restrict__ mask,
    const unsigned short* __restrict__ vtf,
    float* __restrict__ out1,
    float* __restrict__ part)
{
    __shared__ unsigned short As[2][32 * AP];   // 2 x 8.7 KB
    const int bx  = blockIdx.x;
    const int b   = bx & 7;                     // XCD swizzle
    const int tt  = (bx >> 3) & 7;
    const int kc  = bx >> 6;                    // 0..7, K-chunk 512
    const int t0  = tt * 32;
    const int k0  = kc * 512;
    const int tid = threadIdx.x;
    const int w    = tid >> 6;
    const int lane = tid & 63;
    const int quad = lane >> 4;
    const int l15  = lane & 15;

    const float* mbase = mask + (size_t)b * TGT * SRC + (size_t)t0 * SRC + k0;
    float*       obase = out1 + (size_t)b * TGT * SRC + (size_t)t0 * SRC + k0;
    const int sr0 = tid >> 5, sr1 = sr0 + 16, sc = (tid & 31) * 4;

    // wave w owns e columns [w*32, w*32+32): et pair (2w, 2w+1)
    const unsigned short* bfr0 = vtf + (((size_t)b * 16 + 2 * w) * 128 + (size_t)kc * 16) * 512;
    const unsigned short* bfr1 = bfr0 + (size_t)128 * 512;

    // ---- prologue: ONE burst of all 8 mask loads (mv[2s]=row sr0, mv[2s+1]=row sr1)
    f4 mv[8];
    #pragma unroll
    for (int s = 0; s < 4; ++s) {
        mv[2 * s]     = *(const f4*)(mbase + (size_t)sr0 * SRC + s * 128 + sc);
        mv[2 * s + 1] = *(const f4*)(mbase + (size_t)sr1 * SRC + s * 128 + sc);
    }

    // stage 0: out1 copy + cvt into As[0]  (waits only vmcnt for mv[0..1])
    {
        *(f4*)(obase + (size_t)sr0 * SRC + sc) = mv[0];
        *(f4*)(obase + (size_t)sr1 * SRC + sc) = mv[1];
        u16x4 p0, p1;
        #pragma unroll
        for (int j = 0; j < 4; ++j) { p0[j] = f2b(mv[0][j]); p1[j] = f2b(mv[1][j]); }
        *(u16x4*)&As[0][sr0 * AP + sc] = p0;
        *(u16x4*)&As[0][sr1 * AP + sc] = p1;
    }
    __syncthreads();

    f32x4 acc00 = {}, acc01 = {}, acc10 = {}, acc11 = {};

    #pragma unroll
    for (int s = 0; s < 4; ++s) {               // 4 stages x 128 k
        #pragma unroll
        for (int q = 0; q < 4; ++q) {
            bf16x8 B0 = *(const bf16x8*)(bfr0 + ((size_t)(s * 4 + q) * 64 + lane) * 8);
            bf16x8 B1 = *(const bf16x8*)(bfr1 + ((size_t)(s * 4 + q) * 64 + lane) * 8);
            bf16x8 a0 = *(const bf16x8*)&As[s & 1][ l15       * AP + q * 32 + quad * 8];
            bf16x8 a1 = *(const bf16x8*)&As[s & 1][(l15 + 16) * AP + q * 32 + quad * 8];
            acc00 = __builtin_amdgcn_mfma_f32_16x16x32_bf16(a0, B0, acc00, 0, 0, 0);
            acc01 = __builtin_amdgcn_mfma_f32_16x16x32_bf16(a0, B1, acc01, 0, 0, 0);
            acc10 = __builtin_amdgcn_mfma_f32_16x16x32_bf16(a1, B0, acc10, 0, 0, 0);
            acc11 = __builtin_amdgcn_mfma_f32_16x16x32_bf16(a1, B1, acc11, 0, 0, 0);
        }
        if (s < 3) {
            *(f4*)(obase + (size_t)sr0 * SRC + (s + 1) * 128 + sc) = mv[2 * s + 2];
            *(f4*)(obase + (size_t)sr1 * SRC + (s + 1) * 128 + sc) = mv[2 * s + 3];
            u16x4 p0, p1;
            #pragma unroll
            for (int j = 0; j < 4; ++j) {
                p0[j] = f2b(mv[2 * s + 2][j]);
                p1[j] = f2b(mv[2 * s + 3][j]);
            }
            *(u16x4*)&As[(s + 1) & 1][sr0 * AP + sc] = p0;
            *(u16x4*)&As[(s + 1) & 1][sr1 * AP + sc] = p1;
        }
        __syncthreads();
    }

    // epilogue: wave-private 32x32 fp32 partial
    // D layout: col = lane&15 (n), row = quad*4 + reg (m)  [verified m89/m91]
    float* pb = part + ((size_t)kc * BSZ + b) * TGT * E;
    #pragma unroll
    for (int r = 0; r < 4; ++r) {
        int rr0 = t0 + quad * 4 + r;
        int rr1 = rr0 + 16;
        int c0  = w * 32 + l15;
        pb[(size_t)rr0 * E + c0]      = acc00[r];
        pb[(size_t)rr0 * E + c0 + 16] = acc01[r];
        pb[(size_t)rr1 * E + c0]      = acc10[r];
        pb[(size_t)rr1 * E + c0 + 16] = acc11[r];
    }
}

// ---------------------------------------------------------------------------
// gemm2_fused: out0[t,b,:] = (sum_kc part[kc])[b,t,:] @ W^T + bias.
// [R0 verbatim — measured-good ~8 us]
// ---------------------------------------------------------------------------
#define PSTRIDE ((size_t)BSZ * TGT * E)

__global__ __launch_bounds__(256) void gemm2_fused(
    const float* __restrict__ part,
    const unsigned short* __restrict__ wf,
    const float* __restrict__ bias,
    float* __restrict__ out0)
{
    __shared__ unsigned short ct[16 * 264];     // 16 t-rows x 256 e, pitch 264
    const int blk  = blockIdx.x;                // 0..127
    const int b    = blk & 7;
    const int tt16 = blk >> 3;                  // 0..15
    const int tid  = threadIdx.x;

    // ---- reduce 8 K-partials into bf16 LDS tile (each element read once)
    const float* pb = part + (size_t)b * TGT * E + (size_t)(tt16 * 16) * E;
    #pragma unroll
    for (int i = 0; i < 4; ++i) {
        int idx = i * 256 + tid;                // 0..1023
        int row = idx >> 6;                     // 0..15
        int c4  = idx & 63;
        const float* ap = pb + (size_t)row * E + c4 * 4;
        f4 s = *(const f4*)ap;
        #pragma unroll
        for (int p = 1; p < 8; ++p) s += *(const f4*)(ap + p * PSTRIDE);
        #pragma unroll
        for (int j = 0; j < 4; ++j) ct[row * 264 + c4 * 4 + j] = f2b(s[j]);
    }
    __syncthreads();

    // ---- MFMA: 4 waves x 4 et tiles each
    const int w    = tid >> 6;
    const int lane = tid & 63;
    const int quad = lane >> 4;
    const int l15  = lane & 15;

    bf16x8 A[8];
    #pragma unroll
    for (int ks = 0; ks < 8; ++ks)
        A[ks] = *(const bf16x8*)&ct[l15 * 264 + ks * 32 + quad * 8];

    #pragma unroll
    for (int e4 = 0; e4 < 4; ++e4) {
        int et = w * 4 + e4;
        const unsigned short* bf = wf + ((size_t)et * 8 * 64 + lane) * 8;
        f32x4 acc = {};
        #pragma unroll
        for (int ks = 0; ks < 8; ++ks) {
            bf16x8 bb = *(const bf16x8*)(bf + (size_t)ks * 512);
            acc = __builtin_amdgcn_mfma_f32_16x16x32_bf16(A[ks], bb, acc, 0, 0, 0);
        }
        const float bval = bias[et * 16 + l15];
        #pragma unroll
        for (int r = 0; r < 4; ++r) {
            int t = tt16 * 16 + quad * 4 + r;
            int e = et * 16 + l15;
            out0[(size_t)t * (BSZ * E) + (size_t)b * E + e] = acc[r] + bval;
        }
    }
}

// ---------------------------------------------------------------------------
extern "C" void kernel_launch(void* const* d_in, const int* in_sizes, int n_in,
                              void* d_out, int out_size, void* d_ws, size_t ws_size,
                              hipStream_t stream)
{
    // inputs: 0=query(unused) 1=key(unused) 2=value 3=proposal_mask 4=W 5=bias
    const float* value = (const float*)d_in[2];
    const float* mask  = (const float*)d_in[3];
    const float* wgt   = (const float*)d_in[4];
    const float* bias  = (const float*)d_in[5];

    float* out0 = (float*)d_out;                              // (256,8,256)
    float* out1 = (float*)d_out + (size_t)TGT * BSZ * E;      // (8,256,4096)

    // ws layout: vtf bf16 16.8MB | wf bf16 128KB | part fp32 [8][b][t][e] 16.8MB
    unsigned short* vtf  = (unsigned short*)d_ws;
    unsigned short* wf   = vtf + (size_t)BSZ * E * SRC;
    float*          part = (float*)(wf + (size_t)16 * 8 * 64 * 8);

    prep<<<dim3(64, 9), 256, 0, stream>>>(value, wgt, vtf, wf);
    gemm1<<<512, 512, 0, stream>>>(mask, vtf, out1, part);
    gemm2_fused<<<128, 256, 0, stream>>>(part, wf, bias, out0);
}